// Round 11
// baseline (312.179 us; speedup 1.0000x reference)
//
#include <hip/hip_runtime.h>

#define IN_DIM 128
#define HID    128
#define NCLS   4

typedef __attribute__((ext_vector_type(8))) short bf16x8;
typedef __attribute__((ext_vector_type(4))) float f32x4;

// ---- fp32 -> bf16 hi/lo split helpers (RNE) ----
__device__ inline ushort f2bf(float x) {
    uint u = __builtin_bit_cast(uint, x);
    u += 0x7FFFu + ((u >> 16) & 1u);
    return (ushort)(u >> 16);
}
__device__ inline float bf2f(ushort h) {
    uint u = ((uint)h) << 16;
    return __builtin_bit_cast(float, u);
}

// async global->LDS, 16B per lane; lptr must be wave-uniform (HW adds lane*16)
__device__ inline void gload_lds16(const void* g, void* l) {
    __builtin_amdgcn_global_load_lds((const __attribute__((address_space(1))) void*)g,
                                     (__attribute__((address_space(3))) void*)l, 16, 0, 0);
}

// ---------------- cast W0 and W1 (each 128x128) ----------------
__global__ __launch_bounds__(256) void cast_w(const float* __restrict__ W0,
                                              const float* __restrict__ W1,
                                              ushort* __restrict__ w0h, ushort* __restrict__ w0l,
                                              ushort* __restrict__ w1h, ushort* __restrict__ w1l)
{
    int i = blockIdx.x * 256 + threadIdx.x;     // 0..32767
    float v = (i < 16384) ? W0[i] : W1[i - 16384];
    ushort h = f2bf(v);
    ushort l = f2bf(v - bf2f(h));
    if (i < 16384) { w0h[i] = h; w0l[i] = l; }
    else           { w1h[i - 16384] = h; w1l[i - 16384] = l; }
}

// LDS tile layout (both GEMMs): [64 rows][16 units of 16B], swizzled unit = u ^ (row&7).
// hi plane at lds[0..16384), lo plane at lds[16384..32768).

// ---------------- Layer 0 body: H = relu(X @ W0^T + b0) for 64 rows at bm ----------------
__device__ __forceinline__ void lin0_body(const float* __restrict__ X,
                                          const ushort* __restrict__ Whi,
                                          const ushort* __restrict__ Wlo,
                                          const float* __restrict__ Bv,
                                          ushort* __restrict__ Hhi,
                                          ushort* __restrict__ Hlo,
                                          int M, int bm, char* lds)
{
    const int tid = threadIdx.x;

    // ---- stage 64 rows x 128 k ----
    {
        const int row  = tid >> 2;               // 0..63
        const int seg  = tid & 3;                // which 32-elem chunk of the row
        const int grow = min(bm + row, M - 1);   // clamp: dup row, masked later
        const float4* src = (const float4*)((const char*)X + (size_t)grow * 512 + seg * 128);
        float4 v[8];
        #pragma unroll
        for (int j = 0; j < 8; ++j) v[j] = src[j];

        #pragma unroll
        for (int j = 0; j < 4; ++j) {            // 4 units of 8 elems
            uint hw[4], lw[4];
            #pragma unroll
            for (int q = 0; q < 2; ++q) {
                const float4 f = v[j * 2 + q];
                ushort h0 = f2bf(f.x), h1 = f2bf(f.y), h2 = f2bf(f.z), h3 = f2bf(f.w);
                ushort l0 = f2bf(f.x - bf2f(h0)), l1 = f2bf(f.y - bf2f(h1));
                ushort l2 = f2bf(f.z - bf2f(h2)), l3 = f2bf(f.w - bf2f(h3));
                hw[q * 2]     = (uint)h0 | ((uint)h1 << 16);
                hw[q * 2 + 1] = (uint)h2 | ((uint)h3 << 16);
                lw[q * 2]     = (uint)l0 | ((uint)l1 << 16);
                lw[q * 2 + 1] = (uint)l2 | ((uint)l3 << 16);
            }
            int unit = (seg * 4 + j) ^ (row & 7);
            int off  = row * 256 + unit * 16;
            *(uint4*)(lds + off)         = make_uint4(hw[0], hw[1], hw[2], hw[3]);
            *(uint4*)(lds + 16384 + off) = make_uint4(lw[0], lw[1], lw[2], lw[3]);
        }
    }
    __syncthreads();

    const int wid = tid >> 6, lane = tid & 63;
    const int wr = wid >> 1, wc = wid & 1;
    const int colbase = wc * 64;
    const int lr = lane & 15, lk = lane >> 4;

    f32x4 acc[4][2];
    #pragma unroll
    for (int nt = 0; nt < 4; ++nt)
        #pragma unroll
        for (int rt = 0; rt < 2; ++rt) acc[nt][rt] = (f32x4){0.f, 0.f, 0.f, 0.f};

    #pragma unroll
    for (int kt = 0; kt < 4; ++kt) {
        const int ko = kt * 32 + lk * 8;
        bf16x8 xh[2], xl[2];
        #pragma unroll
        for (int rt = 0; rt < 2; ++rt) {
            int lrow = wr * 32 + rt * 16 + lr;
            int unit = (kt * 4 + lk) ^ (lrow & 7);
            int off  = lrow * 256 + unit * 16;
            xh[rt] = *(const bf16x8*)(lds + off);
            xl[rt] = *(const bf16x8*)(lds + 16384 + off);
        }
        #pragma unroll
        for (int nt = 0; nt < 4; ++nt) {
            size_t bo = (size_t)(colbase + nt * 16 + lr) * 128 + ko;
            bf16x8 wh = *(const bf16x8*)(Whi + bo);
            bf16x8 wl = *(const bf16x8*)(Wlo + bo);
            #pragma unroll
            for (int rt = 0; rt < 2; ++rt) {
                acc[nt][rt] = __builtin_amdgcn_mfma_f32_16x16x32_bf16(wh, xh[rt], acc[nt][rt], 0, 0, 0);
                acc[nt][rt] = __builtin_amdgcn_mfma_f32_16x16x32_bf16(wh, xl[rt], acc[nt][rt], 0, 0, 0);
                acc[nt][rt] = __builtin_amdgcn_mfma_f32_16x16x32_bf16(wl, xh[rt], acc[nt][rt], 0, 0, 0);
            }
        }
    }

    #pragma unroll
    for (int nt = 0; nt < 4; ++nt) {
        const int col0 = colbase + nt * 16 + lk * 4;
        const float4 bv4 = *(const float4*)(Bv + col0);
        const float bvv[4] = {bv4.x, bv4.y, bv4.z, bv4.w};
        #pragma unroll
        for (int rt = 0; rt < 2; ++rt) {
            int row = bm + wr * 32 + rt * 16 + lr;
            float o0 = fmaxf(acc[nt][rt][0] + bvv[0], 0.f);
            float o1 = fmaxf(acc[nt][rt][1] + bvv[1], 0.f);
            float o2 = fmaxf(acc[nt][rt][2] + bvv[2], 0.f);
            float o3 = fmaxf(acc[nt][rt][3] + bvv[3], 0.f);
            ushort4 h4, l4;
            h4.x = f2bf(o0); l4.x = f2bf(o0 - bf2f(h4.x));
            h4.y = f2bf(o1); l4.y = f2bf(o1 - bf2f(h4.y));
            h4.z = f2bf(o2); l4.z = f2bf(o2 - bf2f(h4.z));
            h4.w = f2bf(o3); l4.w = f2bf(o3 - bf2f(h4.w));
            size_t oo = (size_t)row * 128 + col0;
            *(ushort4*)(Hhi + oo) = h4;
            *(ushort4*)(Hlo + oo) = l4;
        }
    }
}

// ---------------- K_A: lin0 most  ||  count_deg ----------------
__global__ __launch_bounds__(256) void k_lin0_count(const float* __restrict__ X,
                                                    const ushort* __restrict__ Whi,
                                                    const ushort* __restrict__ Wlo,
                                                    const float* __restrict__ Bv,
                                                    ushort* __restrict__ Hhi,
                                                    ushort* __restrict__ Hlo, int M,
                                                    int nLin0,
                                                    const int* __restrict__ rows,
                                                    int* __restrict__ deg, int E)
{
    __shared__ uint4 lds4[2048];                 // 32 KiB
    if ((int)blockIdx.x < nLin0) {
        lin0_body(X, Whi, Wlo, Bv, Hhi, Hlo, M, blockIdx.x * 64, (char*)lds4);
    } else {
        int e = (blockIdx.x - nLin0) * 256 + threadIdx.x;
        if (e < E) atomicAdd(&deg[rows[e]], 1);
    }
}

// ---------------- alloc_off: contiguous range per row via wave-aggregated cursor ----
// CSR consumers only need disjoint contiguous ranges, NOT row-ordered offsets.
__global__ __launch_bounds__(256) void alloc_off(const int* __restrict__ deg,
                                                 int* __restrict__ off,
                                                 int* __restrict__ pos,
                                                 int* __restrict__ cursor, int M)
{
    int i = blockIdx.x * 256 + threadIdx.x;
    int lane = threadIdx.x & 63;
    int d = (i < M) ? deg[i] : 0;
    int v = d;
    #pragma unroll
    for (int o = 1; o < 64; o <<= 1) {
        int t = __shfl_up(v, o);
        if (lane >= o) v += t;
    }
    int b = 0;
    if (lane == 63) b = atomicAdd(cursor, v);    // v at lane63 = wave total
    b = __shfl(b, 63);
    if (i < M) {
        int o = b + v - d;                        // exclusive within wave + base
        off[i] = o;
        pos[i] = o;
    }
}

// ---------------- K_B: lin0 rest  ||  fill_csr (plain stores) ----------------
__global__ __launch_bounds__(256) void k_lin0_fill(const float* __restrict__ X,
                                                   const ushort* __restrict__ Whi,
                                                   const ushort* __restrict__ Wlo,
                                                   const float* __restrict__ Bv,
                                                   ushort* __restrict__ Hhi,
                                                   ushort* __restrict__ Hlo, int M,
                                                   int nLin0, int baseLin0,
                                                   const int* __restrict__ rows,
                                                   const int* __restrict__ cols,
                                                   int* __restrict__ pos,
                                                   int* __restrict__ col_sorted, int E)
{
    __shared__ uint4 lds4[2048];                 // 32 KiB
    if ((int)blockIdx.x < nLin0) {
        lin0_body(X, Whi, Wlo, Bv, Hhi, Hlo, M, (baseLin0 + blockIdx.x) * 64, (char*)lds4);
    } else {
        int e = (blockIdx.x - nLin0) * 256 + threadIdx.x;
        if (e < E) {
            int p = atomicAdd(&pos[rows[e]], 1);
            col_sorted[p] = cols[e];
        }
    }
}

// ---------------- Layer 1 + classifier ----------------
__global__ __launch_bounds__(256) void gnn_lin1_mfma(const ushort* __restrict__ Ahi,
                                                     const ushort* __restrict__ Alo,
                                                     const ushort* __restrict__ Whi,
                                                     const ushort* __restrict__ Wlo,
                                                     const float* __restrict__ Bv,
                                                     const float* __restrict__ Wc,
                                                     const float* __restrict__ bc,
                                                     float* __restrict__ Out, int M)
{
    __shared__ uint4 lds4[2048];                 // 32 KiB
    __shared__ float red[2][64][4];
    char* lds = (char*)lds4;

    const int tid = threadIdx.x;
    const int wid = tid >> 6, lane = tid & 63;
    const int bm  = blockIdx.x * 64;

    // ---- stage: waves 0,1 fill hi plane; waves 2,3 fill lo plane ----
    #pragma unroll
    for (int i = 0; i < 8; ++i) {
        int o = wid * 8192 + i * 1024 + lane * 16;       // linear LDS byte this lane fills
        const ushort* plane = (o < 16384) ? Ahi : Alo;   // wave-uniform select
        int po   = o & 16383;
        int row  = po >> 8;
        int unit = (po >> 4) & 15;
        const char* src = (const char*)plane + (size_t)(bm + row) * 256
                        + ((unit ^ (row & 7)) << 4);     // pre-swizzled source
        gload_lds16(src, lds + wid * 8192 + i * 1024);   // wave-uniform dest
    }
    __syncthreads();

    const int wr = wid >> 1, wc = wid & 1;
    const int colbase = wc * 64;
    const int lr = lane & 15, lk = lane >> 4;

    f32x4 acc[4][2];
    #pragma unroll
    for (int nt = 0; nt < 4; ++nt)
        #pragma unroll
        for (int rt = 0; rt < 2; ++rt) acc[nt][rt] = (f32x4){0.f, 0.f, 0.f, 0.f};

    #pragma unroll
    for (int kt = 0; kt < 4; ++kt) {
        const int ko = kt * 32 + lk * 8;
        bf16x8 xh[2], xl[2];
        #pragma unroll
        for (int rt = 0; rt < 2; ++rt) {
            int lrow = wr * 32 + rt * 16 + lr;
            int unit = (kt * 4 + lk) ^ (lrow & 7);
            int off  = lrow * 256 + unit * 16;
            xh[rt] = *(const bf16x8*)(lds + off);
            xl[rt] = *(const bf16x8*)(lds + 16384 + off);
        }
        #pragma unroll
        for (int nt = 0; nt < 4; ++nt) {
            size_t bo = (size_t)(colbase + nt * 16 + lr) * 128 + ko;
            bf16x8 wh = *(const bf16x8*)(Whi + bo);
            bf16x8 wl = *(const bf16x8*)(Wlo + bo);
            #pragma unroll
            for (int rt = 0; rt < 2; ++rt) {
                acc[nt][rt] = __builtin_amdgcn_mfma_f32_16x16x32_bf16(wh, xh[rt], acc[nt][rt], 0, 0, 0);
                acc[nt][rt] = __builtin_amdgcn_mfma_f32_16x16x32_bf16(wh, xl[rt], acc[nt][rt], 0, 0, 0);
                acc[nt][rt] = __builtin_amdgcn_mfma_f32_16x16x32_bf16(wl, xh[rt], acc[nt][rt], 0, 0, 0);
            }
        }
    }

    // h2 = relu(acc + b1); per-lane classifier partial over its 16 cols
    float p[2][4] = {{0.f, 0.f, 0.f, 0.f}, {0.f, 0.f, 0.f, 0.f}};
    #pragma unroll
    for (int nt = 0; nt < 4; ++nt) {
        const int col0 = colbase + nt * 16 + lk * 4;
        const float4 bv4 = *(const float4*)(Bv + col0);
        const float bvv[4] = {bv4.x, bv4.y, bv4.z, bv4.w};
        float4 wcr[4];
        #pragma unroll
        for (int c = 0; c < 4; ++c) wcr[c] = *(const float4*)(Wc + c * HID + col0);
        #pragma unroll
        for (int rt = 0; rt < 2; ++rt) {
            float h2v[4];
            #pragma unroll
            for (int r = 0; r < 4; ++r) h2v[r] = fmaxf(acc[nt][rt][r] + bvv[r], 0.f);
            #pragma unroll
            for (int c = 0; c < 4; ++c) {
                const float* w = (const float*)&wcr[c];
                p[rt][c] = fmaf(h2v[0], w[0], p[rt][c]);
                p[rt][c] = fmaf(h2v[1], w[1], p[rt][c]);
                p[rt][c] = fmaf(h2v[2], w[2], p[rt][c]);
                p[rt][c] = fmaf(h2v[3], w[3], p[rt][c]);
            }
        }
    }
    #pragma unroll
    for (int offs = 16; offs < 64; offs <<= 1)
        #pragma unroll
        for (int rt = 0; rt < 2; ++rt)
            #pragma unroll
            for (int c = 0; c < 4; ++c)
                p[rt][c] += __shfl_xor(p[rt][c], offs);

    if (lk == 0) {
        #pragma unroll
        for (int rt = 0; rt < 2; ++rt) {
            f32x4 v = {p[rt][0], p[rt][1], p[rt][2], p[rt][3]};
            *(f32x4*)&red[wc][wr * 32 + rt * 16 + lr][0] = v;
        }
    }
    __syncthreads();

    const int row_local = tid >> 2, cls = tid & 3;
    int row = blockIdx.x * 64 + row_local;
    if (row < M) {
        float s = bc[cls] + red[0][row_local][cls] + red[1][row_local][cls];
        Out[(size_t)row * 4 + cls] = s;
    }
}

// ---------------- Aggregation ----------------
__global__ __launch_bounds__(256) void gnn_aggregate(const ushort* __restrict__ Hhi,
                                                     const ushort* __restrict__ Hlo,
                                                     const int* __restrict__ off,
                                                     const int* __restrict__ deg,
                                                     const int* __restrict__ col_sorted,
                                                     ushort* __restrict__ InHi,
                                                     ushort* __restrict__ InLo,
                                                     int M, int Mpad)
{
    int gid  = blockIdx.x * 8 + (threadIdx.x >> 5);
    int lane = threadIdx.x & 31;
    if (gid >= Mpad) return;
    size_t oidx = (size_t)gid * 32 + lane;   // ushort4 index
    if (gid >= M) {
        ((ushort4*)InHi)[oidx] = make_ushort4(0, 0, 0, 0);
        ((ushort4*)InLo)[oidx] = make_ushort4(0, 0, 0, 0);
        return;
    }

    const ushort4* G = (const ushort4*)Hhi;
    int start = off[gid];
    int d     = deg[gid];
    int end   = start + d;

    float s0[4] = {0.f, 0.f, 0.f, 0.f};
    float s1[4] = {0.f, 0.f, 0.f, 0.f};
    float s2[4] = {0.f, 0.f, 0.f, 0.f};
    float s3[4] = {0.f, 0.f, 0.f, 0.f};
    int e = start;
    for (; e + 4 <= end; e += 4) {
        int c0 = col_sorted[e], c1 = col_sorted[e + 1];
        int c2 = col_sorted[e + 2], c3 = col_sorted[e + 3];
        ushort4 g0 = G[(size_t)c0 * 32 + lane];
        ushort4 g1 = G[(size_t)c1 * 32 + lane];
        ushort4 g2 = G[(size_t)c2 * 32 + lane];
        ushort4 g3 = G[(size_t)c3 * 32 + lane];
        s0[0] += bf2f(g0.x); s0[1] += bf2f(g0.y); s0[2] += bf2f(g0.z); s0[3] += bf2f(g0.w);
        s1[0] += bf2f(g1.x); s1[1] += bf2f(g1.y); s1[2] += bf2f(g1.z); s1[3] += bf2f(g1.w);
        s2[0] += bf2f(g2.x); s2[1] += bf2f(g2.y); s2[2] += bf2f(g2.z); s2[3] += bf2f(g2.w);
        s3[0] += bf2f(g3.x); s3[1] += bf2f(g3.y); s3[2] += bf2f(g3.z); s3[3] += bf2f(g3.w);
    }
    for (; e < end; ++e) {
        int c0 = col_sorted[e];
        ushort4 g0 = G[(size_t)c0 * 32 + lane];
        s0[0] += bf2f(g0.x); s0[1] += bf2f(g0.y); s0[2] += bf2f(g0.z); s0[3] += bf2f(g0.w);
    }
    float a0 = (s0[0] + s1[0]) + (s2[0] + s3[0]);
    float a1 = (s0[1] + s1[1]) + (s2[1] + s3[1]);
    float a2 = (s0[2] + s1[2]) + (s2[2] + s3[2]);
    float a3 = (s0[3] + s1[3]) + (s2[3] + s3[3]);

    float inv = 1.0f / fmaxf((float)d, 1.0f);
    ushort4 rh = ((const ushort4*)Hhi)[oidx];
    ushort4 rl = ((const ushort4*)Hlo)[oidx];
    float o0 = bf2f(rh.x) + bf2f(rl.x) + a0 * inv;
    float o1 = bf2f(rh.y) + bf2f(rl.y) + a1 * inv;
    float o2 = bf2f(rh.z) + bf2f(rl.z) + a2 * inv;
    float o3 = bf2f(rh.w) + bf2f(rl.w) + a3 * inv;

    ushort4 h4, l4;
    h4.x = f2bf(o0); l4.x = f2bf(o0 - bf2f(h4.x));
    h4.y = f2bf(o1); l4.y = f2bf(o1 - bf2f(h4.y));
    h4.z = f2bf(o2); l4.z = f2bf(o2 - bf2f(h4.z));
    h4.w = f2bf(o3); l4.w = f2bf(o3 - bf2f(h4.w));
    ((ushort4*)InHi)[oidx] = h4;
    ((ushort4*)InLo)[oidx] = l4;
}

extern "C" void kernel_launch(void* const* d_in, const int* in_sizes, int n_in,
                              void* d_out, int out_size, void* d_ws, size_t ws_size,
                              hipStream_t stream)
{
    const float* x  = (const float*)d_in[0];
    const int*   ei = (const int*)  d_in[1];
    const float* W0 = (const float*)d_in[2];
    const float* b0 = (const float*)d_in[3];
    const float* W1 = (const float*)d_in[4];
    const float* b1 = (const float*)d_in[5];
    const float* Wc = (const float*)d_in[6];
    const float* bc = (const float*)d_in[7];
    float* out = (float*)d_out;

    const int M    = in_sizes[0] / IN_DIM;   // 100000
    const int E    = in_sizes[1] / 2;        // 800000
    const int Mpad = (M + 63) & ~63;         // 100032

    // workspace layout
    ushort* Hhi  = (ushort*)d_ws;                        // Mpad*128
    ushort* Hlo  = Hhi  + (size_t)Mpad * 128;
    ushort* InHi = Hlo  + (size_t)Mpad * 128;
    ushort* InLo = InHi + (size_t)Mpad * 128;
    ushort* W0h  = InLo + (size_t)Mpad * 128;            // 16384 each
    ushort* W0l  = W0h + 16384;
    ushort* W1h  = W0l + 16384;
    ushort* W1l  = W1h + 16384;
    int* deg_i   = (int*)(W1l + 16384);                  // M
    int* cursor  = deg_i + M;                            // 16 (padded)
    int* off     = cursor + 16;                          // M
    int* pos     = off + M;                              // M
    int* col_sorted = pos + M;                           // E

    const int* rows = ei;
    const int* cols = ei + E;

    // zero deg + cursor
    hipMemsetAsync(deg_i, 0, (size_t)(M + 16) * sizeof(int), stream);

    const int gridMM = Mpad / 64;            // 1563
    const int nA     = 1250;                 // lin0 blocks in K_A
    const int nB     = gridMM - nA;          // 313 in K_B
    const int gridE  = (E + 255) / 256;      // 3125
    const int gridN  = (M + 255) / 256;      // 391

    cast_w<<<128, 256, 0, stream>>>(W0, W1, W0h, W0l, W1h, W1l);

    // K_A: lin0 rows [0, nA*64)  ||  count_deg
    k_lin0_count<<<nA + gridE, 256, 0, stream>>>(x, W0h, W0l, b0, Hhi, Hlo, M,
                                                 nA, rows, deg_i, E);

    alloc_off<<<gridN, 256, 0, stream>>>(deg_i, off, pos, cursor, M);

    // K_B: lin0 rows [nA*64, Mpad)  ||  fill_csr
    k_lin0_fill<<<nB + gridE, 256, 0, stream>>>(x, W0h, W0l, b0, Hhi, Hlo, M,
                                                nB, nA, rows, cols, pos, col_sorted, E);

    gnn_aggregate<<<(Mpad + 7) / 8, 256, 0, stream>>>(Hhi, Hlo, off, deg_i, col_sorted,
                                                      InHi, InLo, M, Mpad);
    gnn_lin1_mfma<<<gridMM, 256, 0, stream>>>(InHi, InLo, W1h, W1l, b1, Wc, bc, out, M);
}

// Round 12
// 292.927 us; speedup vs baseline: 1.0657x; 1.0657x over previous
//
#include <hip/hip_runtime.h>

#define IN_DIM 128
#define HID    128
#define NCLS   4

typedef __attribute__((ext_vector_type(8))) short bf16x8;
typedef __attribute__((ext_vector_type(4))) float f32x4;

// ---- fp32 -> bf16 hi/lo split helpers (RNE) ----
__device__ inline ushort f2bf(float x) {
    uint u = __builtin_bit_cast(uint, x);
    u += 0x7FFFu + ((u >> 16) & 1u);
    return (ushort)(u >> 16);
}
__device__ inline float bf2f(ushort h) {
    uint u = ((uint)h) << 16;
    return __builtin_bit_cast(float, u);
}

// async global->LDS, 16B per lane; lptr must be wave-uniform (HW adds lane*16)
__device__ inline void gload_lds16(const void* g, void* l) {
    __builtin_amdgcn_global_load_lds((const __attribute__((address_space(1))) void*)g,
                                     (__attribute__((address_space(3))) void*)l, 16, 0, 0);
}

// ---------------- cast W0 and W1 (each 128x128) ----------------
__global__ __launch_bounds__(256) void cast_w(const float* __restrict__ W0,
                                              const float* __restrict__ W1,
                                              ushort* __restrict__ w0h, ushort* __restrict__ w0l,
                                              ushort* __restrict__ w1h, ushort* __restrict__ w1l)
{
    int i = blockIdx.x * 256 + threadIdx.x;     // 0..32767
    float v = (i < 16384) ? W0[i] : W1[i - 16384];
    ushort h = f2bf(v);
    ushort l = f2bf(v - bf2f(h));
    if (i < 16384) { w0h[i] = h; w0l[i] = l; }
    else           { w1h[i - 16384] = h; w1l[i - 16384] = l; }
}

// X LDS tile: [64 rows][16 units of 16B], swizzled unit = u ^ (row&7).
// hi plane at lds[0..16384), lo plane at lds[16384..32768).

// ---------------- Layer 0 body: H = relu(X @ W0^T + b0), bf16 H (hi only) ----------------
__device__ __forceinline__ void lin0_body(const float* __restrict__ X,
                                          const ushort* __restrict__ Whi,
                                          const ushort* __restrict__ Wlo,
                                          const float* __restrict__ Bv,
                                          ushort* __restrict__ Hhi,
                                          int M, int bm, char* lds)
{
    const int tid = threadIdx.x;

    // ---- stage 64 rows x 128 k (X split hi/lo) ----
    {
        const int row  = tid >> 2;               // 0..63
        const int seg  = tid & 3;                // which 32-elem chunk of the row
        const int grow = min(bm + row, M - 1);   // clamp: dup row, masked later
        const float4* src = (const float4*)((const char*)X + (size_t)grow * 512 + seg * 128);
        float4 v[8];
        #pragma unroll
        for (int j = 0; j < 8; ++j) v[j] = src[j];

        #pragma unroll
        for (int j = 0; j < 4; ++j) {            // 4 units of 8 elems
            uint hw[4], lw[4];
            #pragma unroll
            for (int q = 0; q < 2; ++q) {
                const float4 f = v[j * 2 + q];
                ushort h0 = f2bf(f.x), h1 = f2bf(f.y), h2 = f2bf(f.z), h3 = f2bf(f.w);
                ushort l0 = f2bf(f.x - bf2f(h0)), l1 = f2bf(f.y - bf2f(h1));
                ushort l2 = f2bf(f.z - bf2f(h2)), l3 = f2bf(f.w - bf2f(h3));
                hw[q * 2]     = (uint)h0 | ((uint)h1 << 16);
                hw[q * 2 + 1] = (uint)h2 | ((uint)h3 << 16);
                lw[q * 2]     = (uint)l0 | ((uint)l1 << 16);
                lw[q * 2 + 1] = (uint)l2 | ((uint)l3 << 16);
            }
            int unit = (seg * 4 + j) ^ (row & 7);
            int off  = row * 256 + unit * 16;
            *(uint4*)(lds + off)         = make_uint4(hw[0], hw[1], hw[2], hw[3]);
            *(uint4*)(lds + 16384 + off) = make_uint4(lw[0], lw[1], lw[2], lw[3]);
        }
    }
    __syncthreads();

    const int wid = tid >> 6, lane = tid & 63;
    const int wr = wid >> 1, wc = wid & 1;
    const int colbase = wc * 64;
    const int lr = lane & 15, lk = lane >> 4;

    f32x4 acc[4][2];
    #pragma unroll
    for (int nt = 0; nt < 4; ++nt)
        #pragma unroll
        for (int rt = 0; rt < 2; ++rt) acc[nt][rt] = (f32x4){0.f, 0.f, 0.f, 0.f};

    #pragma unroll
    for (int kt = 0; kt < 4; ++kt) {
        const int ko = kt * 32 + lk * 8;
        bf16x8 xh[2], xl[2];
        #pragma unroll
        for (int rt = 0; rt < 2; ++rt) {
            int lrow = wr * 32 + rt * 16 + lr;
            int unit = (kt * 4 + lk) ^ (lrow & 7);
            int off  = lrow * 256 + unit * 16;
            xh[rt] = *(const bf16x8*)(lds + off);
            xl[rt] = *(const bf16x8*)(lds + 16384 + off);
        }
        #pragma unroll
        for (int nt = 0; nt < 4; ++nt) {
            size_t bo = (size_t)(colbase + nt * 16 + lr) * 128 + ko;
            bf16x8 wh = *(const bf16x8*)(Whi + bo);
            bf16x8 wl = *(const bf16x8*)(Wlo + bo);
            #pragma unroll
            for (int rt = 0; rt < 2; ++rt) {
                acc[nt][rt] = __builtin_amdgcn_mfma_f32_16x16x32_bf16(wh, xh[rt], acc[nt][rt], 0, 0, 0);
                acc[nt][rt] = __builtin_amdgcn_mfma_f32_16x16x32_bf16(wh, xl[rt], acc[nt][rt], 0, 0, 0);
                acc[nt][rt] = __builtin_amdgcn_mfma_f32_16x16x32_bf16(wl, xh[rt], acc[nt][rt], 0, 0, 0);
            }
        }
    }

    #pragma unroll
    for (int nt = 0; nt < 4; ++nt) {
        const int col0 = colbase + nt * 16 + lk * 4;
        const float4 bv4 = *(const float4*)(Bv + col0);
        const float bvv[4] = {bv4.x, bv4.y, bv4.z, bv4.w};
        #pragma unroll
        for (int rt = 0; rt < 2; ++rt) {
            int row = bm + wr * 32 + rt * 16 + lr;
            float o0 = fmaxf(acc[nt][rt][0] + bvv[0], 0.f);
            float o1 = fmaxf(acc[nt][rt][1] + bvv[1], 0.f);
            float o2 = fmaxf(acc[nt][rt][2] + bvv[2], 0.f);
            float o3 = fmaxf(acc[nt][rt][3] + bvv[3], 0.f);
            ushort4 h4;
            h4.x = f2bf(o0); h4.y = f2bf(o1); h4.z = f2bf(o2); h4.w = f2bf(o3);
            *(ushort4*)(Hhi + (size_t)row * 128 + col0) = h4;
        }
    }
}

// ---------------- K_A: lin0 first half  ||  count_deg ----------------
__global__ __launch_bounds__(256) void k_lin0_count(const float* __restrict__ X,
                                                    const ushort* __restrict__ Whi,
                                                    const ushort* __restrict__ Wlo,
                                                    const float* __restrict__ Bv,
                                                    ushort* __restrict__ Hhi, int M,
                                                    int nLin0,
                                                    const int* __restrict__ rows,
                                                    int* __restrict__ deg, int E)
{
    __shared__ uint4 lds4[2048];                 // 32 KiB
    if ((int)blockIdx.x < nLin0) {
        lin0_body(X, Whi, Wlo, Bv, Hhi, M, blockIdx.x * 64, (char*)lds4);
    } else {
        int e = (blockIdx.x - nLin0) * 256 + threadIdx.x;
        if (e < E) atomicAdd(&deg[rows[e]], 1);
    }
}

// ---------------- alloc_off: contiguous range per row via wave-aggregated cursor ----
__global__ __launch_bounds__(256) void alloc_off(const int* __restrict__ deg,
                                                 int* __restrict__ off,
                                                 int* __restrict__ pos,
                                                 int* __restrict__ cursor, int M)
{
    int i = blockIdx.x * 256 + threadIdx.x;
    int lane = threadIdx.x & 63;
    int d = (i < M) ? deg[i] : 0;
    int v = d;
    #pragma unroll
    for (int o = 1; o < 64; o <<= 1) {
        int t = __shfl_up(v, o);
        if (lane >= o) v += t;
    }
    int b = 0;
    if (lane == 63) b = atomicAdd(cursor, v);    // v at lane63 = wave total
    b = __shfl(b, 63);
    if (i < M) {
        int o = b + v - d;                        // exclusive within wave + base
        off[i] = o;
        pos[i] = o;
    }
}

// ---------------- K_B: lin0 second half  ||  fill_csr ----------------
__global__ __launch_bounds__(256) void k_lin0_fill(const float* __restrict__ X,
                                                   const ushort* __restrict__ Whi,
                                                   const ushort* __restrict__ Wlo,
                                                   const float* __restrict__ Bv,
                                                   ushort* __restrict__ Hhi, int M,
                                                   int nLin0, int baseLin0,
                                                   const int* __restrict__ rows,
                                                   const int* __restrict__ cols,
                                                   int* __restrict__ pos,
                                                   int* __restrict__ col_sorted, int E)
{
    __shared__ uint4 lds4[2048];                 // 32 KiB
    if ((int)blockIdx.x < nLin0) {
        lin0_body(X, Whi, Wlo, Bv, Hhi, M, (baseLin0 + blockIdx.x) * 64, (char*)lds4);
    } else {
        int e = (blockIdx.x - nLin0) * 256 + threadIdx.x;
        if (e < E) {
            int p = atomicAdd(&pos[rows[e]], 1);
            col_sorted[p] = cols[e];
        }
    }
}

// ---------------- Aggregation: In = bf16(h + gather_sum(Hhi)/max(deg,1)) ----------------
__global__ __launch_bounds__(256) void gnn_aggregate(const ushort* __restrict__ Hhi,
                                                     const int* __restrict__ off,
                                                     const int* __restrict__ deg,
                                                     const int* __restrict__ col_sorted,
                                                     ushort* __restrict__ InHi,
                                                     int M, int Mpad)
{
    int gid  = blockIdx.x * 8 + (threadIdx.x >> 5);
    int lane = threadIdx.x & 31;
    if (gid >= Mpad) return;
    size_t oidx = (size_t)gid * 32 + lane;   // ushort4 index
    if (gid >= M) {
        ((ushort4*)InHi)[oidx] = make_ushort4(0, 0, 0, 0);
        return;
    }

    const ushort4* G = (const ushort4*)Hhi;
    int start = off[gid];
    int d     = deg[gid];
    int end   = start + d;

    float s0[4] = {0.f, 0.f, 0.f, 0.f};
    float s1[4] = {0.f, 0.f, 0.f, 0.f};
    float s2[4] = {0.f, 0.f, 0.f, 0.f};
    float s3[4] = {0.f, 0.f, 0.f, 0.f};
    int e = start;
    for (; e + 4 <= end; e += 4) {
        int c0 = col_sorted[e], c1 = col_sorted[e + 1];
        int c2 = col_sorted[e + 2], c3 = col_sorted[e + 3];
        ushort4 g0 = G[(size_t)c0 * 32 + lane];
        ushort4 g1 = G[(size_t)c1 * 32 + lane];
        ushort4 g2 = G[(size_t)c2 * 32 + lane];
        ushort4 g3 = G[(size_t)c3 * 32 + lane];
        s0[0] += bf2f(g0.x); s0[1] += bf2f(g0.y); s0[2] += bf2f(g0.z); s0[3] += bf2f(g0.w);
        s1[0] += bf2f(g1.x); s1[1] += bf2f(g1.y); s1[2] += bf2f(g1.z); s1[3] += bf2f(g1.w);
        s2[0] += bf2f(g2.x); s2[1] += bf2f(g2.y); s2[2] += bf2f(g2.z); s2[3] += bf2f(g2.w);
        s3[0] += bf2f(g3.x); s3[1] += bf2f(g3.y); s3[2] += bf2f(g3.z); s3[3] += bf2f(g3.w);
    }
    for (; e < end; ++e) {
        int c0 = col_sorted[e];
        ushort4 g0 = G[(size_t)c0 * 32 + lane];
        s0[0] += bf2f(g0.x); s0[1] += bf2f(g0.y); s0[2] += bf2f(g0.z); s0[3] += bf2f(g0.w);
    }
    float a0 = (s0[0] + s1[0]) + (s2[0] + s3[0]);
    float a1 = (s0[1] + s1[1]) + (s2[1] + s3[1]);
    float a2 = (s0[2] + s1[2]) + (s2[2] + s3[2]);
    float a3 = (s0[3] + s1[3]) + (s2[3] + s3[3]);

    float inv = 1.0f / fmaxf((float)d, 1.0f);
    ushort4 rh = ((const ushort4*)Hhi)[oidx];
    float o0 = bf2f(rh.x) + a0 * inv;
    float o1 = bf2f(rh.y) + a1 * inv;
    float o2 = bf2f(rh.z) + a2 * inv;
    float o3 = bf2f(rh.w) + a3 * inv;

    ushort4 h4;
    h4.x = f2bf(o0); h4.y = f2bf(o1); h4.z = f2bf(o2); h4.w = f2bf(o3);
    ((ushort4*)InHi)[oidx] = h4;
}

// ---------------- Layer 1 + classifier: In is single bf16 plane ----------------
__global__ __launch_bounds__(256) void gnn_lin1_mfma(const ushort* __restrict__ Ain,
                                                     const ushort* __restrict__ Whi,
                                                     const ushort* __restrict__ Wlo,
                                                     const float* __restrict__ Bv,
                                                     const float* __restrict__ Wc,
                                                     const float* __restrict__ bc,
                                                     float* __restrict__ Out, int M)
{
    __shared__ uint4 lds4[1024];                 // 16 KiB
    __shared__ float red[2][64][4];
    char* lds = (char*)lds4;

    const int tid = threadIdx.x;
    const int wid = tid >> 6, lane = tid & 63;
    const int bm  = blockIdx.x * 64;

    // ---- stage 16 KiB via global_load_lds with PRE-SWIZZLED source ----
    #pragma unroll
    for (int i = 0; i < 4; ++i) {
        int o = wid * 4096 + i * 1024 + lane * 16;       // linear LDS byte
        int row  = o >> 8;
        int unit = (o >> 4) & 15;
        const char* src = (const char*)Ain + (size_t)(bm + row) * 256
                        + ((unit ^ (row & 7)) << 4);     // pre-swizzled source
        gload_lds16(src, lds + wid * 4096 + i * 1024);   // wave-uniform dest
    }
    __syncthreads();

    const int wr = wid >> 1, wc = wid & 1;
    const int colbase = wc * 64;
    const int lr = lane & 15, lk = lane >> 4;

    f32x4 acc[4][2];
    #pragma unroll
    for (int nt = 0; nt < 4; ++nt)
        #pragma unroll
        for (int rt = 0; rt < 2; ++rt) acc[nt][rt] = (f32x4){0.f, 0.f, 0.f, 0.f};

    #pragma unroll
    for (int kt = 0; kt < 4; ++kt) {
        const int ko = kt * 32 + lk * 8;
        bf16x8 xh[2];
        #pragma unroll
        for (int rt = 0; rt < 2; ++rt) {
            int lrow = wr * 32 + rt * 16 + lr;
            int unit = (kt * 4 + lk) ^ (lrow & 7);
            xh[rt] = *(const bf16x8*)(lds + lrow * 256 + unit * 16);
        }
        #pragma unroll
        for (int nt = 0; nt < 4; ++nt) {
            size_t bo = (size_t)(colbase + nt * 16 + lr) * 128 + ko;
            bf16x8 wh = *(const bf16x8*)(Whi + bo);
            bf16x8 wl = *(const bf16x8*)(Wlo + bo);
            #pragma unroll
            for (int rt = 0; rt < 2; ++rt) {
                acc[nt][rt] = __builtin_amdgcn_mfma_f32_16x16x32_bf16(wh, xh[rt], acc[nt][rt], 0, 0, 0);
                acc[nt][rt] = __builtin_amdgcn_mfma_f32_16x16x32_bf16(wl, xh[rt], acc[nt][rt], 0, 0, 0);
            }
        }
    }

    // h2 = relu(acc + b1); per-lane classifier partial over its 16 cols
    float p[2][4] = {{0.f, 0.f, 0.f, 0.f}, {0.f, 0.f, 0.f, 0.f}};
    #pragma unroll
    for (int nt = 0; nt < 4; ++nt) {
        const int col0 = colbase + nt * 16 + lk * 4;
        const float4 bv4 = *(const float4*)(Bv + col0);
        const float bvv[4] = {bv4.x, bv4.y, bv4.z, bv4.w};
        float4 wcr[4];
        #pragma unroll
        for (int c = 0; c < 4; ++c) wcr[c] = *(const float4*)(Wc + c * HID + col0);
        #pragma unroll
        for (int rt = 0; rt < 2; ++rt) {
            float h2v[4];
            #pragma unroll
            for (int r = 0; r < 4; ++r) h2v[r] = fmaxf(acc[nt][rt][r] + bvv[r], 0.f);
            #pragma unroll
            for (int c = 0; c < 4; ++c) {
                const float* w = (const float*)&wcr[c];
                p[rt][c] = fmaf(h2v[0], w[0], p[rt][c]);
                p[rt][c] = fmaf(h2v[1], w[1], p[rt][c]);
                p[rt][c] = fmaf(h2v[2], w[2], p[rt][c]);
                p[rt][c] = fmaf(h2v[3], w[3], p[rt][c]);
            }
        }
    }
    #pragma unroll
    for (int offs = 16; offs < 64; offs <<= 1)
        #pragma unroll
        for (int rt = 0; rt < 2; ++rt)
            #pragma unroll
            for (int c = 0; c < 4; ++c)
                p[rt][c] += __shfl_xor(p[rt][c], offs);

    if (lk == 0) {
        #pragma unroll
        for (int rt = 0; rt < 2; ++rt) {
            f32x4 v = {p[rt][0], p[rt][1], p[rt][2], p[rt][3]};
            *(f32x4*)&red[wc][wr * 32 + rt * 16 + lr][0] = v;
        }
    }
    __syncthreads();

    const int row_local = tid >> 2, cls = tid & 3;
    int row = blockIdx.x * 64 + row_local;
    if (row < M) {
        float s = bc[cls] + red[0][row_local][cls] + red[1][row_local][cls];
        Out[(size_t)row * 4 + cls] = s;
    }
}

extern "C" void kernel_launch(void* const* d_in, const int* in_sizes, int n_in,
                              void* d_out, int out_size, void* d_ws, size_t ws_size,
                              hipStream_t stream)
{
    const float* x  = (const float*)d_in[0];
    const int*   ei = (const int*)  d_in[1];
    const float* W0 = (const float*)d_in[2];
    const float* b0 = (const float*)d_in[3];
    const float* W1 = (const float*)d_in[4];
    const float* b1 = (const float*)d_in[5];
    const float* Wc = (const float*)d_in[6];
    const float* bc = (const float*)d_in[7];
    float* out = (float*)d_out;

    const int M    = in_sizes[0] / IN_DIM;   // 100000
    const int E    = in_sizes[1] / 2;        // 800000
    const int Mpad = (M + 63) & ~63;         // 100032

    // workspace layout
    ushort* Hhi  = (ushort*)d_ws;                        // Mpad*128
    ushort* InHi = Hhi  + (size_t)Mpad * 128;            // Mpad*128
    ushort* W0h  = InHi + (size_t)Mpad * 128;            // 16384 each
    ushort* W0l  = W0h + 16384;
    ushort* W1h  = W0l + 16384;
    ushort* W1l  = W1h + 16384;
    int* deg_i   = (int*)(W1l + 16384);                  // M
    int* cursor  = deg_i + M;                            // 16 (padded)
    int* off     = cursor + 16;                          // M
    int* pos     = off + M;                              // M
    int* col_sorted = pos + M;                           // E

    const int* rows = ei;
    const int* cols = ei + E;

    // zero deg + cursor
    hipMemsetAsync(deg_i, 0, (size_t)(M + 16) * sizeof(int), stream);

    const int gridMM = Mpad / 64;            // 1563
    const int nA     = (gridMM + 1) / 2;     // 782
    const int nB     = gridMM - nA;          // 781
    const int gridE  = (E + 255) / 256;      // 3125
    const int gridN  = (M + 255) / 256;      // 391

    cast_w<<<128, 256, 0, stream>>>(W0, W1, W0h, W0l, W1h, W1l);

    // K_A: lin0 rows [0, nA*64)  ||  count_deg
    k_lin0_count<<<nA + gridE, 256, 0, stream>>>(x, W0h, W0l, b0, Hhi, M,
                                                 nA, rows, deg_i, E);

    alloc_off<<<gridN, 256, 0, stream>>>(deg_i, off, pos, cursor, M);

    // K_B: lin0 rows [nA*64, Mpad)  ||  fill_csr
    k_lin0_fill<<<nB + gridE, 256, 0, stream>>>(x, W0h, W0l, b0, Hhi, M,
                                                nB, nA, rows, cols, pos, col_sorted, E);

    gnn_aggregate<<<(Mpad + 7) / 8, 256, 0, stream>>>(Hhi, off, deg_i, col_sorted,
                                                      InHi, M, Mpad);
    gnn_lin1_mfma<<<gridMM, 256, 0, stream>>>(InHi, W1h, W1l, b1, Wc, bc, out, M);
}